// Round 13
// baseline (6912.336 us; speedup 1.0000x reference)
//
#include <hip/hip_runtime.h>
#include <stdint.h>

#define BB 256
#define TT 512
#define HH 512
#define NBLK 256
#define SSTR 16
#define BBHH (BB*HH)

typedef __bf16 bf16x8 __attribute__((ext_vector_type(8)));
typedef float f32x4 __attribute__((ext_vector_type(4)));
typedef unsigned int u32x2 __attribute__((ext_vector_type(2)));

static __device__ __forceinline__ unsigned short f2bf(float f) {
    unsigned int u = __builtin_bit_cast(unsigned int, f);
    return (unsigned short)((u + 0x7fffu + ((u >> 16) & 1u)) >> 16);
}
static __device__ __forceinline__ bf16x8 packbf8(const float* p) {
    float4 a = *reinterpret_cast<const float4*>(p);
    float4 b = *reinterpret_cast<const float4*>(p + 4);
    unsigned short us[8] = { f2bf(a.x), f2bf(a.y), f2bf(a.z), f2bf(a.w),
                             f2bf(b.x), f2bf(b.y), f2bf(b.z), f2bf(b.w) };
    uint4 u; __builtin_memcpy(&u, us, 16);
    return __builtin_bit_cast(bf16x8, u);
}
static __device__ __forceinline__ float sigm(float x){ return 1.0f/(1.0f+__expf(-x)); }
static __device__ __forceinline__ float tanh_fast(float x){ return 2.0f/(1.0f+__expf(-2.0f*x)) - 1.0f; }

// system-coherent (LLC) path — PROVEN primitives
static __device__ __forceinline__ void ld_sys(uint4& d, const void* p) {
    asm volatile("global_load_dwordx4 %0, %1, off sc0 sc1" : "=v"(d) : "v"(p));
}
static __device__ __forceinline__ void st_sys2(void* p, u32x2 v) {
    asm volatile("global_store_dwordx2 %0, %1, off sc0 sc1" :: "v"(p), "v"(v) : "memory");
}
#define WAITVM(N) asm volatile("s_waitcnt vmcnt(" #N ")" ::: "memory")
#define SBAR      __builtin_amdgcn_sched_barrier(0)

__global__ __launch_bounds__(256) void prep_zero(unsigned short* __restrict__ h1p3,
                                                 unsigned short* __restrict__ h2p1,
                                                 int* __restrict__ slots) {
    int i = blockIdx.x * blockDim.x + threadIdx.x;
    for (int k = i; k < BBHH; k += gridDim.x * blockDim.x) { h1p3[k] = 0; h2p1[k] = 0; }
    slots[i] = 0;   // 64*256 = 16384 = NBLK*4*SSTR exactly
}

// Persistent pipelined 2-layer LSTM — R7-proven body, PER-WAVE decoupled sync.
// 256 blocks x 256 thr (1 block/CU, 1 wave/SIMD, 256 VGPR + AGPR wb, no spill).
// Groups of 32 rows: 16 L0 blocks (bid=g*16+cs) + 16 L1 blocks (bid=128+g*16+cs),
// tile 32 rows x 32 cols. L0 wave w: K-quarter (128) of Whh0 (wb 128 regs).
// L1 wave w: (mm=w>>1, kh=w&1) K-half (256) of (mm? Whh1:Wih1) (wb 256 regs, AGPR).
// SYNC (per-WAVE slot = (bid*4+w)*16; value = completed supersteps, L0 s+1 / L1 s):
//   release: per-wave vmcnt(0) drain -> lane0 publishes own slot (no syncthreads)
//   acquire: all waves poll; lane l (bb=l>>2, ww=l&3) polls own-layer slot(bb,ww)
//            and other-layer slot(bb,ww): L0@ns needs L0>=ns, L1>=ns-3 (h1 4-deep);
//            L1@ns needs L1>=ns-1, L0>=ns. SBAR fences loads after poll.
// Only 2 block-wide syncthreads per step remain (around the LDS reduce).
__global__ __launch_bounds__(256, 1) void lstm_persist(
    const float* __restrict__ x,        // [B][T]
    const float* __restrict__ wih0,     // [2048]
    const float* __restrict__ Whh0,     // [2048][512] f32
    const float* __restrict__ Wih1,     // [2048][512] f32
    const float* __restrict__ Whh1,     // [2048][512] f32
    unsigned short* __restrict__ h1buf, // 4 x [B][H] bf16 (parity t&3)
    unsigned short* __restrict__ h2buf, // 2 x [B][H] bf16 (parity t&1)
    int* __restrict__ slots)            // [256 blk][4 wave] stride-16 ints
{
    __shared__ float xf[16384];         // 64 KB

    const int tid = threadIdx.x;
    const int w   = tid >> 6;
    const int l   = tid & 63;
    const int ln  = l & 15;
    const int kq  = l >> 4;
    const int bid = blockIdx.x;
    const bool isL0 = bid < 128;

    int g, cs, k0, mm = 0;
    const float* Wsrc;
    if (isL0) {
        g = bid >> 4; cs = bid & 15;
        k0 = w * 128;
        Wsrc = Whh0;
    } else {
        const int q = bid - 128;
        g = q >> 4; cs = q & 15;
        mm = w >> 1;
        k0 = (w & 1) * 256;
        Wsrc = mm ? Whh1 : Wih1;
    }
    const int NKB = isL0 ? 4 : 8;

    // ---- one-time weight preload (L0: 128 regs, L1: 256 regs; AGPR-backed) ----
    bf16x8 wb[2][8][4];
    #pragma unroll
    for (int nt = 0; nt < 2; ++nt)
        for (int kb = 0; kb < NKB; ++kb)
            #pragma unroll
            for (int g4 = 0; g4 < 4; ++g4)
                wb[nt][kb][g4] = packbf8(Wsrc + (size_t)(g4 * HH + cs * 32 + nt * 16 + ln) * HH + k0 + kb * 32 + kq * 8);

    // epilogue constants: wave w owns rows w*8..w*8+7 of the group tile
    const int erow = g * 32 + w * 8 + (l >> 3);
    f32x4 wiv[4] = {};
    if (isL0) {
        #pragma unroll
        for (int j = 0; j < 4; ++j) {
            const int cg = cs * 32 + (l & 7) * 4 + j;
            wiv[j] = (f32x4){ wih0[cg], wih0[512 + cg], wih0[1024 + cg], wih0[1536 + cg] };
        }
    }
    const int rt_r = w >> 1;
    const int rowl = (w & 1) * 8 + (l >> 3);
    const int nt_r = (l >> 2) & 1;
    const int colb = (l & 3) * 4;

    // per-lane poll targets: bb = l>>2 (peer block in group), ww = l&3 (peer wave)
    const int bb = l >> 2, ww = l & 3;
    const int sidL0 = ((g * 16 + bb) * 4 + ww) * SSTR;         // L0 peer wave slot
    const int sidL1 = ((128 + g * 16 + bb) * 4 + ww) * SSTR;   // L1 peer wave slot
    int* const myslot = slots + (bid * 4 + w) * SSTR;

    float cst[4] = {0.f, 0.f, 0.f, 0.f};

    for (int s = 0; s <= TT; ++s) {
        const bool active = isL0 ? (s < TT) : (s >= 1);
        if (active) {
            const int t = isL0 ? s : s - 1;
            const unsigned short* hp;
            if (isL0)    hp = h1buf + (size_t)((t - 1) & 3) * BBHH;  // h1_{t-1}
            else if (mm) hp = h2buf + (size_t)((t - 1) & 1) * BBHH;  // h2_{t-1}
            else         hp = h1buf + (size_t)(t & 3) * BBHH;        // h1_t

            f32x4 acc[2][2][4];
            #pragma unroll
            for (int rt = 0; rt < 2; ++rt)
                #pragma unroll
                for (int nt = 0; nt < 2; ++nt)
                    #pragma unroll
                    for (int g4 = 0; g4 < 4; ++g4) acc[rt][nt][g4] = (f32x4){0.f,0.f,0.f,0.f};

            const char* ab = (const char*)(hp + (size_t)(g * 32 + ln) * HH + k0 + kq * 8);
            uint4 A[8][2];

            #define MK(kb) do { \
                _Pragma("unroll") \
                for (int rt = 0; rt < 2; ++rt) { \
                    bf16x8 av = __builtin_bit_cast(bf16x8, A[kb][rt]); \
                    _Pragma("unroll") \
                    for (int nt = 0; nt < 2; ++nt) \
                        _Pragma("unroll") \
                        for (int g4 = 0; g4 < 4; ++g4) \
                            acc[rt][nt][g4] = __builtin_amdgcn_mfma_f32_16x16x32_bf16(av, wb[nt][kb][g4], acc[rt][nt][g4], 0, 0, 0); \
                } } while (0)

            if (isL0) {
                #pragma unroll
                for (int kb = 0; kb < 4; ++kb) {
                    ld_sys(A[kb][0], ab + kb * 64);
                    ld_sys(A[kb][1], ab + 16384 + kb * 64);
                }
                WAITVM(6); SBAR; MK(0);
                WAITVM(4); SBAR; MK(1);
                WAITVM(2); SBAR; MK(2);
                WAITVM(0); SBAR; MK(3);
            } else {
                #pragma unroll
                for (int kb = 0; kb < 8; ++kb) {
                    ld_sys(A[kb][0], ab + kb * 64);
                    ld_sys(A[kb][1], ab + 16384 + kb * 64);
                }
                WAITVM(14); SBAR; MK(0);
                WAITVM(12); SBAR; MK(1);
                WAITVM(10); SBAR; MK(2);
                WAITVM(8);  SBAR; MK(3);
                WAITVM(6);  SBAR; MK(4);
                WAITVM(4);  SBAR; MK(5);
                WAITVM(2);  SBAR; MK(6);
                WAITVM(0);  SBAR; MK(7);
            }
            #undef MK

            // ---- dump all acc to LDS (XOR-swizzled) ----
            __syncthreads();   // all waves done reading xf (prev gather) before overwrite
            #pragma unroll
            for (int rt = 0; rt < 2; ++rt)
                #pragma unroll
                for (int nt = 0; nt < 2; ++nt)
                    #pragma unroll
                    for (int r = 0; r < 4; ++r) {
                        const int row16 = kq * 4 + r;
                        f32x4 v = { acc[rt][nt][0][r], acc[rt][nt][1][r],
                                    acc[rt][nt][2][r], acc[rt][nt][3][r] };
                        *(f32x4*)((char*)xf + (((w * 2 + rt) * 2 + nt) * 16 + row16) * 256
                                            + ((ln * 16) ^ ((row16 & 7) << 4))) = v;
                    }
            __syncthreads();

            // ---- gather 4 slots, cell update, coalesced h store ----
            float xv = 0.f;
            if (isL0) xv = x[(size_t)erow * TT + t];
            unsigned short* ho = isL0 ? (h1buf + (size_t)(t & 3) * BBHH)
                                      : (h2buf + (size_t)(t & 1) * BBHH);
            unsigned short hout[4];
            #pragma unroll
            for (int j = 0; j < 4; ++j) {
                f32x4 sv = (f32x4){0.f, 0.f, 0.f, 0.f};
                #pragma unroll
                for (int s4 = 0; s4 < 4; ++s4)
                    sv += *(const f32x4*)((const char*)xf + (((s4 * 2 + rt_r) * 2 + nt_r) * 16 + rowl) * 256
                                                          + (((colb + j) * 16) ^ ((rowl & 7) << 4)));
                if (isL0) sv += wiv[j] * xv;
                const float c = sigm(sv.y) * cst[j] + sigm(sv.x) * tanh_fast(sv.z);
                cst[j] = c;
                hout[j] = f2bf(sigm(sv.w) * tanh_fast(c));
            }
            u32x2 hv;
            hv.x = (unsigned int)hout[0] | ((unsigned int)hout[1] << 16);
            hv.y = (unsigned int)hout[2] | ((unsigned int)hout[3] << 16);
            st_sys2(ho + (size_t)erow * HH + cs * 32 + (l & 7) * 4, hv);
        }

        // ---- per-wave release + sync-free acquire ----
        if (s < TT) {
            WAITVM(0);               // this wave's h-stores/loads drained
            if (active && l == 0)
                __hip_atomic_store(myslot, isL0 ? s + 1 : s,
                                   __ATOMIC_RELAXED, __HIP_MEMORY_SCOPE_AGENT);
            const int ns = s + 1;
            const bool nextAct = isL0 ? (ns < TT) : true;
            if (nextAct) {
                const int thrOwn = isL0 ? ns : ns - 1;
                const int thrOth = isL0 ? ns - 3 : ns;
                const int* pOwn = slots + (isL0 ? sidL0 : sidL1);
                const int* pOth = slots + (isL0 ? sidL1 : sidL0);
                bool okA = false, okB = false;
                while (true) {
                    if (!okA) okA = __hip_atomic_load(pOwn, __ATOMIC_RELAXED, __HIP_MEMORY_SCOPE_AGENT) >= thrOwn;
                    if (!okB) okB = __hip_atomic_load(pOth, __ATOMIC_RELAXED, __HIP_MEMORY_SCOPE_AGENT) >= thrOth;
                    if (okA && okB) break;
                    __builtin_amdgcn_s_sleep(1);
                }
                SBAR;   // fence: nothing from next step moves above the poll
            }
        }
    }
}

// ---- final: LayerNorm(last h2) @ w_out^T, one 64-lane block per batch row ----
__global__ __launch_bounds__(64) void ln_out_k(const unsigned short* __restrict__ h2,
                                               const float* __restrict__ gamma,
                                               const float* __restrict__ beta,
                                               const float* __restrict__ wout,
                                               float* __restrict__ out)
{
    const int row = blockIdx.x;
    const int lane = threadIdx.x;
    uint4 u = *reinterpret_cast<const uint4*>(h2 + row * HH + lane * 8);
    unsigned short us[8];
    *reinterpret_cast<uint4*>(us) = u;
    float v[8];
    #pragma unroll
    for (int j = 0; j < 8; ++j) {
        unsigned int ww = ((unsigned int)us[j]) << 16;
        v[j] = __builtin_bit_cast(float, ww);
    }
    float sum = 0.f;
    #pragma unroll
    for (int j = 0; j < 8; ++j) sum += v[j];
    #pragma unroll
    for (int o = 32; o >= 1; o >>= 1) sum += __shfl_xor(sum, o);
    const float mu = sum * (1.0f / 512.0f);

    float vs = 0.f;
    #pragma unroll
    for (int j = 0; j < 8; ++j) { float d = v[j] - mu; vs += d * d; }
    #pragma unroll
    for (int o = 32; o >= 1; o >>= 1) vs += __shfl_xor(vs, o);
    const float inv = rsqrtf(vs * (1.0f / 512.0f) + 1e-5f);

    float dot = 0.f;
    #pragma unroll
    for (int j = 0; j < 8; ++j) {
        const int c = lane * 8 + j;
        dot += ((v[j] - mu) * inv * gamma[c] + beta[c]) * wout[c];
    }
    #pragma unroll
    for (int o = 32; o >= 1; o >>= 1) dot += __shfl_xor(dot, o);
    if (lane == 0) out[row] = dot;
}

extern "C" void kernel_launch(void* const* d_in, const int* in_sizes, int n_in,
                              void* d_out, int out_size, void* d_ws, size_t ws_size,
                              hipStream_t stream) {
    const float* x     = (const float*)d_in[0];
    const float* wih0  = (const float*)d_in[1];
    const float* whh0  = (const float*)d_in[2];
    const float* wih1  = (const float*)d_in[3];
    const float* whh1  = (const float*)d_in[4];
    const float* gamma = (const float*)d_in[5];
    const float* beta  = (const float*)d_in[6];
    const float* wout  = (const float*)d_in[7];

    // ws layout: h1buf 4x256KB | h2buf 2x256KB | slots 64KB
    char* ws = (char*)d_ws;
    unsigned short* h1buf = (unsigned short*)(ws);
    unsigned short* h2buf = (unsigned short*)(ws + (1024u << 10));
    int* slots            = (int*)(ws + (1536u << 10));

    hipLaunchKernelGGL(prep_zero, dim3(64), dim3(256), 0, stream,
                       h1buf + 3 * (size_t)BBHH, h2buf + BBHH, slots);

    hipLaunchKernelGGL(lstm_persist, dim3(NBLK), dim3(256), 0, stream,
                       x, wih0, whh0, wih1, whh1, h1buf, h2buf, slots);

    // final h2 is parity (T-1)&1 == 1
    hipLaunchKernelGGL(ln_out_k, dim3(BB), dim3(64), 0, stream,
                       h2buf + BBHH, gamma, beta, wout, (float*)d_out);
}

// Round 14
// 4690.429 us; speedup vs baseline: 1.4737x; 1.4737x over previous
//
#include <hip/hip_runtime.h>
#include <stdint.h>

#define BB 256
#define TT 512
#define HH 512
#define NBLK 256
#define SSTR 16
#define BBHH (BB*HH)

typedef __bf16 bf16x8 __attribute__((ext_vector_type(8)));
typedef float f32x4 __attribute__((ext_vector_type(4)));
typedef unsigned int u32x2 __attribute__((ext_vector_type(2)));

static __device__ __forceinline__ unsigned short f2bf(float f) {
    unsigned int u = __builtin_bit_cast(unsigned int, f);
    return (unsigned short)((u + 0x7fffu + ((u >> 16) & 1u)) >> 16);
}
static __device__ __forceinline__ bf16x8 packbf8(const float* p) {
    float4 a = *reinterpret_cast<const float4*>(p);
    float4 b = *reinterpret_cast<const float4*>(p + 4);
    unsigned short us[8] = { f2bf(a.x), f2bf(a.y), f2bf(a.z), f2bf(a.w),
                             f2bf(b.x), f2bf(b.y), f2bf(b.z), f2bf(b.w) };
    uint4 u; __builtin_memcpy(&u, us, 16);
    return __builtin_bit_cast(bf16x8, u);
}
static __device__ __forceinline__ float sigm(float x){ return 1.0f/(1.0f+__expf(-x)); }
static __device__ __forceinline__ float tanh_fast(float x){ return 2.0f/(1.0f+__expf(-2.0f*x)) - 1.0f; }

// CACHED h path (new): normal loads/stores, L2 write-back. Coherence comes from
// agent-scope fences at the barrier (release: wbl2; acquire: inv) — the exact
// compiler-generated sequence proven correct end-to-end in R2.
static __device__ __forceinline__ void ld_c(uint4& d, const void* p) {
    asm volatile("global_load_dwordx4 %0, %1, off" : "=v"(d) : "v"(p));
}
static __device__ __forceinline__ void st_c2(void* p, u32x2 v) {
    asm volatile("global_store_dwordx2 %0, %1, off" :: "v"(p), "v"(v) : "memory");
}
#define WAITVM(N) asm volatile("s_waitcnt vmcnt(" #N ")" ::: "memory")
#define SBAR      __builtin_amdgcn_sched_barrier(0)

__global__ __launch_bounds__(256) void prep_zero(unsigned short* __restrict__ h1p3,
                                                 unsigned short* __restrict__ h2p1,
                                                 int* __restrict__ slots) {
    int i = blockIdx.x * blockDim.x + threadIdx.x;
    for (int k = i; k < BBHH; k += gridDim.x * blockDim.x) { h1p3[k] = 0; h2p1[k] = 0; }
    if (i < NBLK * SSTR) slots[i] = 0;
}

// Persistent pipelined 2-layer LSTM — R11-proven body (no-spill shape: A[4][2]
// rolling refill, 256 thr, bounds(256,1), wb in AGPRs) with FENCE-BASED cached
// h exchange. 8 groups of 32 rows; 16 L0 blocks (bid=g*16+cs) + 16 L1 blocks
// (bid=128+g*16+cs); tile 32 rows x 32 cols. L0 wave w: K-quarter of Whh0
// (wb 128 regs). L1 wave w: (mm=w>>1, kh=w&1) K-half of (mm? Whh1:Wih1)
// (wb 256 regs). Reduce: all-dump 64KB LDS (XOR-swizzled), gather, lane-owned c,
// 8B/lane cached store.
// SYNC (decoupled slots, values = completed supersteps; L0 stores s+1, L1 stores s):
//   release: per-wave vmcnt(0) (stores in L2) -> syncthreads -> tid0:
//            fence(release,agent) [wbl2] + relaxed agent slot store
//   acquire: tid<32 poll peers; wave0 fence(acquire,agent) [inv L1+L2]; syncthreads
//   L0@ns: L0 peers >= ns, L1 peers >= ns-3 (h1 4-deep).  L1@ns: L0 >= ns, L1 >= ns-1.
__global__ __launch_bounds__(256, 1) void lstm_persist(
    const float* __restrict__ x,        // [B][T]
    const float* __restrict__ wih0,     // [2048]
    const float* __restrict__ Whh0,     // [2048][512] f32
    const float* __restrict__ Wih1,     // [2048][512] f32
    const float* __restrict__ Whh1,     // [2048][512] f32
    unsigned short* __restrict__ h1buf, // 4 x [B][H] bf16 (parity t&3)
    unsigned short* __restrict__ h2buf, // 2 x [B][H] bf16 (parity t&1)
    int* __restrict__ slots)
{
    __shared__ float xf[16384];         // 64 KB

    const int tid = threadIdx.x;
    const int w   = tid >> 6;
    const int l   = tid & 63;
    const int ln  = l & 15;
    const int kq  = l >> 4;
    const int bid = blockIdx.x;
    const bool isL0 = bid < 128;

    int g, cs, k0, mm = 0;
    const float* Wsrc;
    if (isL0) {
        g = bid >> 4; cs = bid & 15;
        k0 = w * 128;
        Wsrc = Whh0;
    } else {
        const int q = bid - 128;
        g = q >> 4; cs = q & 15;
        mm = w >> 1;
        k0 = (w & 1) * 256;
        Wsrc = mm ? Whh1 : Wih1;
    }

    // ---- one-time weight preload (L0: 128 regs, L1: 256 regs; AGPR-backed) ----
    bf16x8 wb[2][8][4];
    if (isL0) {
        #pragma unroll
        for (int nt = 0; nt < 2; ++nt)
            #pragma unroll
            for (int kb = 0; kb < 4; ++kb)
                #pragma unroll
                for (int g4 = 0; g4 < 4; ++g4)
                    wb[nt][kb][g4] = packbf8(Wsrc + (size_t)(g4 * HH + cs * 32 + nt * 16 + ln) * HH + k0 + kb * 32 + kq * 8);
    } else {
        #pragma unroll
        for (int nt = 0; nt < 2; ++nt)
            #pragma unroll
            for (int kb = 0; kb < 8; ++kb)
                #pragma unroll
                for (int g4 = 0; g4 < 4; ++g4)
                    wb[nt][kb][g4] = packbf8(Wsrc + (size_t)(g4 * HH + cs * 32 + nt * 16 + ln) * HH + k0 + kb * 32 + kq * 8);
    }

    // epilogue constants: lane owns row erow, cols cs*32 + (l&7)*4 + 0..3
    const int erow = g * 32 + w * 8 + (l >> 3);
    f32x4 wiv[4] = {};
    if (isL0) {
        #pragma unroll
        for (int j = 0; j < 4; ++j) {
            const int cg = cs * 32 + (l & 7) * 4 + j;
            wiv[j] = (f32x4){ wih0[cg], wih0[512 + cg], wih0[1024 + cg], wih0[1536 + cg] };
        }
    }
    const int rt_r = w >> 1;
    const int rowl = (w & 1) * 8 + (l >> 3);
    const int nt_r = (l >> 2) & 1;
    const int colb = (l & 3) * 4;

    float cst[4] = {0.f, 0.f, 0.f, 0.f};

    for (int s = 0; s <= TT; ++s) {
        const bool active = isL0 ? (s < TT) : (s >= 1);
        if (active) {
            const int t = isL0 ? s : s - 1;
            const unsigned short* hp;
            if (isL0)    hp = h1buf + (size_t)((t - 1) & 3) * BBHH;  // h1_{t-1}
            else if (mm) hp = h2buf + (size_t)((t - 1) & 1) * BBHH;  // h2_{t-1}
            else         hp = h1buf + (size_t)(t & 3) * BBHH;        // h1_t

            float xv = 0.f;
            if (isL0) xv = x[(size_t)erow * TT + t];

            f32x4 acc[2][2][4];
            #pragma unroll
            for (int rt = 0; rt < 2; ++rt)
                #pragma unroll
                for (int nt = 0; nt < 2; ++nt)
                    #pragma unroll
                    for (int g4 = 0; g4 < 4; ++g4) acc[rt][nt][g4] = (f32x4){0.f,0.f,0.f,0.f};

            const char* ab = (const char*)(hp + (size_t)(g * 32 + ln) * HH + k0 + kq * 8);
            uint4 A[4][2];
            #pragma unroll
            for (int kb = 0; kb < 4; ++kb) {
                ld_c(A[kb][0], ab + kb * 64);
                ld_c(A[kb][1], ab + 16384 + kb * 64);
            }

            #define MK(kb, ap) do { \
                _Pragma("unroll") \
                for (int rt = 0; rt < 2; ++rt) { \
                    bf16x8 av = __builtin_bit_cast(bf16x8, A[ap][rt]); \
                    _Pragma("unroll") \
                    for (int nt = 0; nt < 2; ++nt) \
                        _Pragma("unroll") \
                        for (int g4 = 0; g4 < 4; ++g4) \
                            acc[rt][nt][g4] = __builtin_amdgcn_mfma_f32_16x16x32_bf16(av, wb[nt][kb][g4], acc[rt][nt][g4], 0, 0, 0); \
                } } while (0)

            if (isL0) {
                WAITVM(6); SBAR; MK(0, 0);
                WAITVM(4); SBAR; MK(1, 1);
                WAITVM(2); SBAR; MK(2, 2);
                WAITVM(0); SBAR; MK(3, 3);
            } else {
                WAITVM(6); SBAR; MK(0, 0);
                ld_c(A[0][0], ab + 256); ld_c(A[0][1], ab + 16384 + 256);
                WAITVM(6); SBAR; MK(1, 1);
                ld_c(A[1][0], ab + 320); ld_c(A[1][1], ab + 16384 + 320);
                WAITVM(6); SBAR; MK(2, 2);
                ld_c(A[2][0], ab + 384); ld_c(A[2][1], ab + 16384 + 384);
                WAITVM(6); SBAR; MK(3, 3);
                ld_c(A[3][0], ab + 448); ld_c(A[3][1], ab + 16384 + 448);
                WAITVM(6); SBAR; MK(4, 0);
                WAITVM(4); SBAR; MK(5, 1);
                WAITVM(2); SBAR; MK(6, 2);
                WAITVM(0); SBAR; MK(7, 3);
            }
            #undef MK

            // ---- dump all acc to LDS (XOR-swizzled) ----
            #pragma unroll
            for (int rt = 0; rt < 2; ++rt)
                #pragma unroll
                for (int nt = 0; nt < 2; ++nt)
                    #pragma unroll
                    for (int r = 0; r < 4; ++r) {
                        const int row16 = kq * 4 + r;
                        f32x4 v = { acc[rt][nt][0][r], acc[rt][nt][1][r],
                                    acc[rt][nt][2][r], acc[rt][nt][3][r] };
                        *(f32x4*)((char*)xf + (((w * 2 + rt) * 2 + nt) * 16 + row16) * 256
                                            + ((ln * 16) ^ ((row16 & 7) << 4))) = v;
                    }
            __syncthreads();

            // ---- gather 4 slots, cell update, coalesced h store ----
            unsigned short* ho = isL0 ? (h1buf + (size_t)(t & 3) * BBHH)
                                      : (h2buf + (size_t)(t & 1) * BBHH);
            unsigned short hout[4];
            #pragma unroll
            for (int j = 0; j < 4; ++j) {
                f32x4 sv = (f32x4){0.f, 0.f, 0.f, 0.f};
                #pragma unroll
                for (int s4 = 0; s4 < 4; ++s4)
                    sv += *(const f32x4*)((const char*)xf + (((s4 * 2 + rt_r) * 2 + nt_r) * 16 + rowl) * 256
                                                          + (((colb + j) * 16) ^ ((rowl & 7) << 4)));
                if (isL0) sv += wiv[j] * xv;
                const float c = sigm(sv.y) * cst[j] + sigm(sv.x) * tanh_fast(sv.z);
                cst[j] = c;
                hout[j] = f2bf(sigm(sv.w) * tanh_fast(c));
            }
            u32x2 hv;
            hv.x = (unsigned int)hout[0] | ((unsigned int)hout[1] << 16);
            hv.y = (unsigned int)hout[2] | ((unsigned int)hout[3] << 16);
            st_c2(ho + (size_t)erow * HH + cs * 32 + (l & 7) * 4, hv);
        }

        // ---- fence-based release + decoupled layer-local acquire ----
        if (s < TT) {
            WAITVM(0);               // own stores accepted by L2
            __syncthreads();
            if (active && tid == 0) {
                __builtin_amdgcn_fence(__ATOMIC_RELEASE, "agent");   // wbl2: L2 -> LLC
                __hip_atomic_store(slots + bid * SSTR, isL0 ? s + 1 : s,
                                   __ATOMIC_RELAXED, __HIP_MEMORY_SCOPE_AGENT);
            }
            const int ns = s + 1;
            const bool nextAct = isL0 ? (ns < TT) : true;
            if (nextAct) {
                if (tid < 32) {
                    const int* sp;
                    int thr;
                    if (tid < 16) {                       // L0 peers of this group
                        sp  = slots + (g * 16 + tid) * SSTR;
                        thr = ns;
                    } else {                              // L1 peers of this group
                        sp  = slots + (128 + g * 16 + (tid - 16)) * SSTR;
                        thr = isL0 ? ns - 3 : ns - 1;
                    }
                    while (__hip_atomic_load(sp, __ATOMIC_RELAXED, __HIP_MEMORY_SCOPE_AGENT) < thr)
                        __builtin_amdgcn_s_sleep(2);
                }
                if (w == 0)
                    __builtin_amdgcn_fence(__ATOMIC_ACQUIRE, "agent");  // inv L1+L2
                SBAR;
                __syncthreads();
            }
        }
    }
}

// ---- final: LayerNorm(last h2) @ w_out^T, one 64-lane block per batch row ----
__global__ __launch_bounds__(64) void ln_out_k(const unsigned short* __restrict__ h2,
                                               const float* __restrict__ gamma,
                                               const float* __restrict__ beta,
                                               const float* __restrict__ wout,
                                               float* __restrict__ out)
{
    const int row = blockIdx.x;
    const int lane = threadIdx.x;
    uint4 u = *reinterpret_cast<const uint4*>(h2 + row * HH + lane * 8);
    unsigned short us[8];
    *reinterpret_cast<uint4*>(us) = u;
    float v[8];
    #pragma unroll
    for (int j = 0; j < 8; ++j) {
        unsigned int ww = ((unsigned int)us[j]) << 16;
        v[j] = __builtin_bit_cast(float, ww);
    }
    float sum = 0.f;
    #pragma unroll
    for (int j = 0; j < 8; ++j) sum += v[j];
    #pragma unroll
    for (int o = 32; o >= 1; o >>= 1) sum += __shfl_xor(sum, o);
    const float mu = sum * (1.0f / 512.0f);

    float vs = 0.f;
    #pragma unroll
    for (int j = 0; j < 8; ++j) { float d = v[j] - mu; vs += d * d; }
    #pragma unroll
    for (int o = 32; o >= 1; o >>= 1) vs += __shfl_xor(vs, o);
    const float inv = rsqrtf(vs * (1.0f / 512.0f) + 1e-5f);

    float dot = 0.f;
    #pragma unroll
    for (int j = 0; j < 8; ++j) {
        const int c = lane * 8 + j;
        dot += ((v[j] - mu) * inv * gamma[c] + beta[c]) * wout[c];
    }
    #pragma unroll
    for (int o = 32; o >= 1; o >>= 1) dot += __shfl_xor(dot, o);
    if (lane == 0) out[row] = dot;
}

extern "C" void kernel_launch(void* const* d_in, const int* in_sizes, int n_in,
                              void* d_out, int out_size, void* d_ws, size_t ws_size,
                              hipStream_t stream) {
    const float* x     = (const float*)d_in[0];
    const float* wih0  = (const float*)d_in[1];
    const float* whh0  = (const float*)d_in[2];
    const float* wih1  = (const float*)d_in[3];
    const float* whh1  = (const float*)d_in[4];
    const float* gamma = (const float*)d_in[5];
    const float* beta  = (const float*)d_in[6];
    const float* wout  = (const float*)d_in[7];

    // ws layout: h1buf 4x256KB | h2buf 2x256KB | slots 16KB
    char* ws = (char*)d_ws;
    unsigned short* h1buf = (unsigned short*)(ws);
    unsigned short* h2buf = (unsigned short*)(ws + (1024u << 10));
    int* slots            = (int*)(ws + (1536u << 10));

    hipLaunchKernelGGL(prep_zero, dim3(64), dim3(256), 0, stream,
                       h1buf + 3 * (size_t)BBHH, h2buf + BBHH, slots);

    hipLaunchKernelGGL(lstm_persist, dim3(NBLK), dim3(256), 0, stream,
                       x, wih0, whh0, wih1, whh1, h1buf, h2buf, slots);

    // final h2 is parity (T-1)&1 == 1
    hipLaunchKernelGGL(ln_out_k, dim3(BB), dim3(64), 0, stream,
                       h2buf + BBHH, gamma, beta, wout, (float*)d_out);
}

// Round 15
// 2690.286 us; speedup vs baseline: 2.5694x; 1.7435x over previous
//
#include <hip/hip_runtime.h>
#include <stdint.h>

#define BB 256
#define TT 512
#define HH 512
#define NBLK 256
#define SSTR 16
#define BBHH (BB*HH)

typedef __bf16 bf16x8 __attribute__((ext_vector_type(8)));
typedef float f32x4 __attribute__((ext_vector_type(4)));
typedef unsigned int u32x2 __attribute__((ext_vector_type(2)));

static __device__ __forceinline__ unsigned short f2bf(float f) {
    unsigned int u = __builtin_bit_cast(unsigned int, f);
    return (unsigned short)((u + 0x7fffu + ((u >> 16) & 1u)) >> 16);
}
static __device__ __forceinline__ bf16x8 packbf8(const float* p) {
    float4 a = *reinterpret_cast<const float4*>(p);
    float4 b = *reinterpret_cast<const float4*>(p + 4);
    unsigned short us[8] = { f2bf(a.x), f2bf(a.y), f2bf(a.z), f2bf(a.w),
                             f2bf(b.x), f2bf(b.y), f2bf(b.z), f2bf(b.w) };
    uint4 u; __builtin_memcpy(&u, us, 16);
    return __builtin_bit_cast(bf16x8, u);
}
static __device__ __forceinline__ float sigm(float x){ return 1.0f/(1.0f+__expf(-x)); }
static __device__ __forceinline__ float tanh_fast(float x){ return 2.0f/(1.0f+__expf(-2.0f*x)) - 1.0f; }

// system-coherent (LLC) path — PROVEN primitives
static __device__ __forceinline__ void ld_sys(uint4& d, const void* p) {
    asm volatile("global_load_dwordx4 %0, %1, off sc0 sc1" : "=v"(d) : "v"(p));
}
static __device__ __forceinline__ void st_sys2(void* p, u32x2 v) {
    asm volatile("global_store_dwordx2 %0, %1, off sc0 sc1" :: "v"(p), "v"(v) : "memory");
}
#define WAITVM(N) asm volatile("s_waitcnt vmcnt(" #N ")" ::: "memory")
#define SBAR      __builtin_amdgcn_sched_barrier(0)

__global__ __launch_bounds__(256) void prep_zero(unsigned short* __restrict__ h1p3,
                                                 unsigned short* __restrict__ h2p1,
                                                 int* __restrict__ slots) {
    int i = blockIdx.x * blockDim.x + threadIdx.x;
    for (int k = i; k < BBHH; k += gridDim.x * blockDim.x) { h1p3[k] = 0; h2p1[k] = 0; }
    if (i < NBLK * SSTR) slots[i] = 0;
}

// Persistent pipelined 2-layer LSTM — R11-proven body with PER-WAVE EARLY acquire.
// 256 blocks x 256 thr (1 block/CU, 1 wave/SIMD, VGPR 256 + AGPR wb, no spill).
// 8 groups of 32 rows; 16 L0 blocks (bid=g*16+cs) + 16 L1 blocks (bid=128+g*16+cs);
// tile 32 rows x 32 cols. L0 wave w: K-quarter of Whh0 (wb 128 regs). L1 wave w:
// (mm=w>>1, kh=w&1) K-half of (mm? Whh1:Wih1) (wb 256 regs).
// SYNC (decoupled slots; value = completed supersteps, L0 publishes s+1, L1 s):
//   release (end of step, unchanged): per-wave vmcnt(0) drain -> syncthreads ->
//     tid0 relaxed agent slot store.
//   acquire (NEW, at START of step s, PER WAVE, before its A-loads):
//     L0 wave:  lanes 0-15 poll L0 peers >= s; lanes 16-31 poll L1 peers >= s-3
//     L1 mm0:   lanes 0-15 poll L0 peers >= s        (h1_t dependency only)
//     L1 mm1:   lanes 0-15 poll L1 peers >= s-1      (h2_{t-1} dependency only)
//   A-loads issue right after the wave's own poll; block join is the existing
//   dump-syncthreads. Step-s polls depend only on step-(s-1) releases -> DAG,
//   no deadlock. h1 4-deep / h2 2-deep race proofs unchanged (reads drained by
//   vmcnt(0) before publish).
__global__ __launch_bounds__(256, 1) void lstm_persist(
    const float* __restrict__ x,        // [B][T]
    const float* __restrict__ wih0,     // [2048]
    const float* __restrict__ Whh0,     // [2048][512] f32
    const float* __restrict__ Wih1,     // [2048][512] f32
    const float* __restrict__ Whh1,     // [2048][512] f32
    unsigned short* __restrict__ h1buf, // 4 x [B][H] bf16 (parity t&3)
    unsigned short* __restrict__ h2buf, // 2 x [B][H] bf16 (parity t&1)
    int* __restrict__ slots)
{
    __shared__ float xf[16384];         // 64 KB

    const int tid = threadIdx.x;
    const int w   = tid >> 6;
    const int l   = tid & 63;
    const int ln  = l & 15;
    const int kq  = l >> 4;
    const int bid = blockIdx.x;
    const bool isL0 = bid < 128;

    int g, cs, k0, mm = 0;
    const float* Wsrc;
    if (isL0) {
        g = bid >> 4; cs = bid & 15;
        k0 = w * 128;
        Wsrc = Whh0;
    } else {
        const int q = bid - 128;
        g = q >> 4; cs = q & 15;
        mm = w >> 1;
        k0 = (w & 1) * 256;
        Wsrc = mm ? Whh1 : Wih1;
    }

    // ---- one-time weight preload (L0: 128 regs, L1: 256 regs; AGPR-backed) ----
    bf16x8 wb[2][8][4];
    if (isL0) {
        #pragma unroll
        for (int nt = 0; nt < 2; ++nt)
            #pragma unroll
            for (int kb = 0; kb < 4; ++kb)
                #pragma unroll
                for (int g4 = 0; g4 < 4; ++g4)
                    wb[nt][kb][g4] = packbf8(Wsrc + (size_t)(g4 * HH + cs * 32 + nt * 16 + ln) * HH + k0 + kb * 32 + kq * 8);
    } else {
        #pragma unroll
        for (int nt = 0; nt < 2; ++nt)
            #pragma unroll
            for (int kb = 0; kb < 8; ++kb)
                #pragma unroll
                for (int g4 = 0; g4 < 4; ++g4)
                    wb[nt][kb][g4] = packbf8(Wsrc + (size_t)(g4 * HH + cs * 32 + nt * 16 + ln) * HH + k0 + kb * 32 + kq * 8);
    }

    // epilogue constants: lane owns row erow, cols cs*32 + (l&7)*4 + 0..3
    const int erow = g * 32 + w * 8 + (l >> 3);
    f32x4 wiv[4] = {};
    if (isL0) {
        #pragma unroll
        for (int j = 0; j < 4; ++j) {
            const int cg = cs * 32 + (l & 7) * 4 + j;
            wiv[j] = (f32x4){ wih0[cg], wih0[512 + cg], wih0[1024 + cg], wih0[1536 + cg] };
        }
    }
    const int rt_r = w >> 1;
    const int rowl = (w & 1) * 8 + (l >> 3);
    const int nt_r = (l >> 2) & 1;
    const int colb = (l & 3) * 4;

    // ---- per-lane poll target + threshold offset (thr = s + thrOff) ----
    const int* pollPtr = nullptr;
    int thrOff = 0;
    if (isL0) {
        if (l < 16)      { pollPtr = slots + (g * 16 + l) * SSTR;           thrOff = 0;  }
        else if (l < 32) { pollPtr = slots + (128 + g * 16 + (l-16)) * SSTR; thrOff = -3; }
    } else if (mm == 0) {
        if (l < 16)      { pollPtr = slots + (g * 16 + l) * SSTR;           thrOff = 0;  }
    } else {
        if (l < 16)      { pollPtr = slots + (128 + g * 16 + l) * SSTR;     thrOff = -1; }
    }

    float cst[4] = {0.f, 0.f, 0.f, 0.f};

    for (int s = 0; s <= TT; ++s) {
        const bool active = isL0 ? (s < TT) : (s >= 1);
        if (active) {
            const int t = isL0 ? s : s - 1;
            const unsigned short* hp;
            if (isL0)    hp = h1buf + (size_t)((t - 1) & 3) * BBHH;  // h1_{t-1}
            else if (mm) hp = h2buf + (size_t)((t - 1) & 1) * BBHH;  // h2_{t-1}
            else         hp = h1buf + (size_t)(t & 3) * BBHH;        // h1_t

            // ---- per-wave acquire for step s (own dependency set only) ----
            if (pollPtr) {
                const int thr = s + thrOff;
                while (__hip_atomic_load(pollPtr, __ATOMIC_RELAXED, __HIP_MEMORY_SCOPE_AGENT) < thr)
                    __builtin_amdgcn_s_sleep(1);
            }
            SBAR;   // nothing below moves above the poll

            float xv = 0.f;
            if (isL0) xv = x[(size_t)erow * TT + t];

            f32x4 acc[2][2][4];
            #pragma unroll
            for (int rt = 0; rt < 2; ++rt)
                #pragma unroll
                for (int nt = 0; nt < 2; ++nt)
                    #pragma unroll
                    for (int g4 = 0; g4 < 4; ++g4) acc[rt][nt][g4] = (f32x4){0.f,0.f,0.f,0.f};

            const char* ab = (const char*)(hp + (size_t)(g * 32 + ln) * HH + k0 + kq * 8);
            uint4 A[4][2];
            #pragma unroll
            for (int kb = 0; kb < 4; ++kb) {
                ld_sys(A[kb][0], ab + kb * 64);
                ld_sys(A[kb][1], ab + 16384 + kb * 64);
            }

            #define MK(kb, ap) do { \
                _Pragma("unroll") \
                for (int rt = 0; rt < 2; ++rt) { \
                    bf16x8 av = __builtin_bit_cast(bf16x8, A[ap][rt]); \
                    _Pragma("unroll") \
                    for (int nt = 0; nt < 2; ++nt) \
                        _Pragma("unroll") \
                        for (int g4 = 0; g4 < 4; ++g4) \
                            acc[rt][nt][g4] = __builtin_amdgcn_mfma_f32_16x16x32_bf16(av, wb[nt][kb][g4], acc[rt][nt][g4], 0, 0, 0); \
                } } while (0)

            if (isL0) {
                WAITVM(6); SBAR; MK(0, 0);
                WAITVM(4); SBAR; MK(1, 1);
                WAITVM(2); SBAR; MK(2, 2);
                WAITVM(0); SBAR; MK(3, 3);
            } else {
                WAITVM(6); SBAR; MK(0, 0);
                ld_sys(A[0][0], ab + 256); ld_sys(A[0][1], ab + 16384 + 256);
                WAITVM(6); SBAR; MK(1, 1);
                ld_sys(A[1][0], ab + 320); ld_sys(A[1][1], ab + 16384 + 320);
                WAITVM(6); SBAR; MK(2, 2);
                ld_sys(A[2][0], ab + 384); ld_sys(A[2][1], ab + 16384 + 384);
                WAITVM(6); SBAR; MK(3, 3);
                ld_sys(A[3][0], ab + 448); ld_sys(A[3][1], ab + 16384 + 448);
                WAITVM(6); SBAR; MK(4, 0);
                WAITVM(4); SBAR; MK(5, 1);
                WAITVM(2); SBAR; MK(6, 2);
                WAITVM(0); SBAR; MK(7, 3);
            }
            #undef MK

            // ---- dump all acc to LDS (XOR-swizzled); join is the sync below ----
            #pragma unroll
            for (int rt = 0; rt < 2; ++rt)
                #pragma unroll
                for (int nt = 0; nt < 2; ++nt)
                    #pragma unroll
                    for (int r = 0; r < 4; ++r) {
                        const int row16 = kq * 4 + r;
                        f32x4 v = { acc[rt][nt][0][r], acc[rt][nt][1][r],
                                    acc[rt][nt][2][r], acc[rt][nt][3][r] };
                        *(f32x4*)((char*)xf + (((w * 2 + rt) * 2 + nt) * 16 + row16) * 256
                                            + ((ln * 16) ^ ((row16 & 7) << 4))) = v;
                    }
            __syncthreads();

            // ---- gather 4 slots, cell update, coalesced h store ----
            unsigned short* ho = isL0 ? (h1buf + (size_t)(t & 3) * BBHH)
                                      : (h2buf + (size_t)(t & 1) * BBHH);
            unsigned short hout[4];
            #pragma unroll
            for (int j = 0; j < 4; ++j) {
                f32x4 sv = (f32x4){0.f, 0.f, 0.f, 0.f};
                #pragma unroll
                for (int s4 = 0; s4 < 4; ++s4)
                    sv += *(const f32x4*)((const char*)xf + (((s4 * 2 + rt_r) * 2 + nt_r) * 16 + rowl) * 256
                                                          + (((colb + j) * 16) ^ ((rowl & 7) << 4)));
                if (isL0) sv += wiv[j] * xv;
                const float c = sigm(sv.y) * cst[j] + sigm(sv.x) * tanh_fast(sv.z);
                cst[j] = c;
                hout[j] = f2bf(sigm(sv.w) * tanh_fast(c));
            }
            u32x2 hv;
            hv.x = (unsigned int)hout[0] | ((unsigned int)hout[1] << 16);
            hv.y = (unsigned int)hout[2] | ((unsigned int)hout[3] << 16);
            st_sys2(ho + (size_t)erow * HH + cs * 32 + (l & 7) * 4, hv);
        }

        // ---- release: drain, join, publish (unchanged; keeps xf-reuse proof) ----
        if (s < TT) {
            WAITVM(0);               // own h-stores AND h-loads drained
            __syncthreads();
            if (active && tid == 0)
                __hip_atomic_store(slots + bid * SSTR, isL0 ? s + 1 : s,
                                   __ATOMIC_RELAXED, __HIP_MEMORY_SCOPE_AGENT);
        }
    }
}

// ---- final: LayerNorm(last h2) @ w_out^T, one 64-lane block per batch row ----
__global__ __launch_bounds__(64) void ln_out_k(const unsigned short* __restrict__ h2,
                                               const float* __restrict__ gamma,
                                               const float* __restrict__ beta,
                                               const float* __restrict__ wout,
                                               float* __restrict__ out)
{
    const int row = blockIdx.x;
    const int lane = threadIdx.x;
    uint4 u = *reinterpret_cast<const uint4*>(h2 + row * HH + lane * 8);
    unsigned short us[8];
    *reinterpret_cast<uint4*>(us) = u;
    float v[8];
    #pragma unroll
    for (int j = 0; j < 8; ++j) {
        unsigned int ww = ((unsigned int)us[j]) << 16;
        v[j] = __builtin_bit_cast(float, ww);
    }
    float sum = 0.f;
    #pragma unroll
    for (int j = 0; j < 8; ++j) sum += v[j];
    #pragma unroll
    for (int o = 32; o >= 1; o >>= 1) sum += __shfl_xor(sum, o);
    const float mu = sum * (1.0f / 512.0f);

    float vs = 0.f;
    #pragma unroll
    for (int j = 0; j < 8; ++j) { float d = v[j] - mu; vs += d * d; }
    #pragma unroll
    for (int o = 32; o >= 1; o >>= 1) vs += __shfl_xor(vs, o);
    const float inv = rsqrtf(vs * (1.0f / 512.0f) + 1e-5f);

    float dot = 0.f;
    #pragma unroll
    for (int j = 0; j < 8; ++j) {
        const int c = lane * 8 + j;
        dot += ((v[j] - mu) * inv * gamma[c] + beta[c]) * wout[c];
    }
    #pragma unroll
    for (int o = 32; o >= 1; o >>= 1) dot += __shfl_xor(dot, o);
    if (lane == 0) out[row] = dot;
}

extern "C" void kernel_launch(void* const* d_in, const int* in_sizes, int n_in,
                              void* d_out, int out_size, void* d_ws, size_t ws_size,
                              hipStream_t stream) {
    const float* x     = (const float*)d_in[0];
    const float* wih0  = (const float*)d_in[1];
    const float* whh0  = (const float*)d_in[2];
    const float* wih1  = (const float*)d_in[3];
    const float* whh1  = (const float*)d_in[4];
    const float* gamma = (const float*)d_in[5];
    const float* beta  = (const float*)d_in[6];
    const float* wout  = (const float*)d_in[7];

    // ws layout: h1buf 4x256KB | h2buf 2x256KB | slots 16KB
    char* ws = (char*)d_ws;
    unsigned short* h1buf = (unsigned short*)(ws);
    unsigned short* h2buf = (unsigned short*)(ws + (1024u << 10));
    int* slots            = (int*)(ws + (1536u << 10));

    hipLaunchKernelGGL(prep_zero, dim3(64), dim3(256), 0, stream,
                       h1buf + 3 * (size_t)BBHH, h2buf + BBHH, slots);

    hipLaunchKernelGGL(lstm_persist, dim3(NBLK), dim3(256), 0, stream,
                       x, wih0, whh0, wih1, whh1, h1buf, h2buf, slots);

    // final h2 is parity (T-1)&1 == 1
    hipLaunchKernelGGL(ln_out_k, dim3(BB), dim3(64), 0, stream,
                       h2buf + BBHH, gamma, beta, wout, (float*)d_out);
}